// Round 6
// baseline (146.710 us; speedup 1.0000x reference)
//
#include <hip/hip_runtime.h>
#include <hip/hip_bf16.h>

#define N_NODES     100000
#define N_NODES_PAD 100096          // 782 * 128
#define NODE_DIM    128
#define N_REL       32
#define N_EDGES_C   500000
#define H_DIM       192             // 3*MLP_DIM
#define P_COLS      384             // 2*H_DIM

typedef __bf16 bf16x8 __attribute__((ext_vector_type(8)));
typedef float  f32x4  __attribute__((ext_vector_type(4)));

__device__ __forceinline__ ushort f2b(float x) {
    __hip_bfloat16 h = __float2bfloat16(x);     // RNE
    return *reinterpret_cast<ushort*>(&h);
}

// unpack a packed pair of bf16 (one u32) into two floats: 1 VALU each
__device__ __forceinline__ void unpack2(unsigned v, float& lo, float& hi) {
    union { unsigned u; float f; } a, b;
    a.u = v << 16;
    b.u = v & 0xffff0000u;
    lo = a.f; hi = b.f;
}

// ---------------------------------------------------------------------------
// Kernel B: Bmat[c][k] = bf16(Beff), c in [0,384), k in [0,128)
//   Beff[c][k] = (c < 192) ? W1[c][k] : W1[c-192][128+k]
// ---------------------------------------------------------------------------
__global__ __launch_bounds__(256) void build_b_kernel(
        const float* __restrict__ W1, ushort* __restrict__ Bmat) {
    int idx = blockIdx.x * 256 + threadIdx.x;      // 49152 total
    if (idx >= P_COLS * NODE_DIM) return;
    int c = idx >> 7, k = idx & 127;
    float v = (c < H_DIM) ? W1[(size_t)c * P_COLS + k]
                          : W1[(size_t)(c - H_DIM) * P_COLS + NODE_DIM + k];
    Bmat[idx] = f2b(v);
}

// ---------------------------------------------------------------------------
// Kernel C: Rb[r][j] = b1[j] + sum_k relation_emb[r][k] * W1[j][256+k]  (f32)
// ---------------------------------------------------------------------------
__global__ void rel_precompute_kernel(const float* __restrict__ rel,
                                      const float* __restrict__ W1,
                                      const float* __restrict__ b1,
                                      float* __restrict__ Rb) {
    int r = blockIdx.x;
    int j = threadIdx.x;           // 0..191
    const float* re = rel + r * NODE_DIM;
    const float* w  = W1 + (size_t)j * P_COLS + 2 * NODE_DIM;
    float acc = b1[j];
    #pragma unroll 8
    for (int k = 0; k < NODE_DIM; ++k)
        acc = fmaf(re[k], w[k], acc);
    Rb[r * H_DIM + j] = acc;
}

// ---------------------------------------------------------------------------
// Kernel D: MFMA GEMM, swapped operands (computes D^T fragment layout).
//   Pb[n][c] = bf16( sum_k all_embed[n][k] * Bmat[c][k] )
// Block: 512 thr = 8 waves (4 row-groups x 2 col-groups).
// Block tile: 128 rows x 192 cols. Wave tile: 32 rows x 96 cols.
//   acc = 2x6 f32x4 = 48 AGPR  ->  ~3 waves/SIMD occupancy.
// mfma(b_frag, a_frag): A-op = Beff rows (P cols), B-op = node rows.
//   D: row = P-col = (lane>>4)*4+reg, col = node-row = lane&15
//   -> lane holds 4 CONSECUTIVE P cols of one node row: pack 2x u32,
//      store as one dwordx2 (12 stores/thread instead of 96 scalar shorts).
// Row indices CLAMPED so all loads are unconditional; stores guarded.
// ---------------------------------------------------------------------------
__global__ __launch_bounds__(512) void node_mfma_kernel(
        const float* __restrict__ embF,
        const ushort* __restrict__ Bmat,
        ushort* __restrict__ Pb) {
    const int tid  = threadIdx.x;
    const int wid  = tid >> 6;
    const int lane = tid & 63;
    const int r16  = lane & 15;
    const int kgrp = lane >> 4;
    const int wr   = wid >> 1;        // row-group 0..3
    const int wc   = wid & 1;         // col-group 0..1

    const int row_base = blockIdx.x * 128 + wr * 32;
    const int colw     = blockIdx.y * 192 + wc * 96;

    const int rowA0 = min(row_base + r16,      N_NODES - 1);
    const int rowA1 = min(row_base + r16 + 16, N_NODES - 1);
    const float* A0 = embF + (size_t)rowA0 * NODE_DIM + kgrp * 8;
    const float* A1 = embF + (size_t)rowA1 * NODE_DIM + kgrp * 8;
    const ushort* Bbase = Bmat + (size_t)(colw + r16) * NODE_DIM + kgrp * 8;

    // ---- prefetch ALL A data: 16 independent 16B HBM loads in flight ----
    float4 af[2][4][2];
    #pragma unroll
    for (int ks = 0; ks < 4; ++ks) {
        af[0][ks][0] = *(const float4*)(A0 + ks * 32);
        af[0][ks][1] = *(const float4*)(A0 + ks * 32 + 4);
        af[1][ks][0] = *(const float4*)(A1 + ks * 32);
        af[1][ks][1] = *(const float4*)(A1 + ks * 32 + 4);
    }

    // ---- convert to bf16 fragments ----
    bf16x8 a[2][4];
    #pragma unroll
    for (int rt = 0; rt < 2; ++rt)
        #pragma unroll
        for (int ks = 0; ks < 4; ++ks) {
            float4 v0 = af[rt][ks][0];
            float4 v1 = af[rt][ks][1];
            bf16x8 r;
            r[0] = (__bf16)v0.x; r[1] = (__bf16)v0.y;
            r[2] = (__bf16)v0.z; r[3] = (__bf16)v0.w;
            r[4] = (__bf16)v1.x; r[5] = (__bf16)v1.y;
            r[6] = (__bf16)v1.z; r[7] = (__bf16)v1.w;
            a[rt][ks] = r;
        }

    // ---- MFMA main loop; B is L2-resident (96 KB table); operands SWAPPED ----
    f32x4 acc[2][6] = {};
    #pragma unroll
    for (int ks = 0; ks < 4; ++ks) {
        #pragma unroll
        for (int ct = 0; ct < 6; ++ct) {
            bf16x8 b = *(const bf16x8*)(Bbase + (size_t)ct * 16 * NODE_DIM + ks * 32);
            acc[0][ct] = __builtin_amdgcn_mfma_f32_16x16x32_bf16(b, a[0][ks], acc[0][ct], 0, 0, 0);
            acc[1][ct] = __builtin_amdgcn_mfma_f32_16x16x32_bf16(b, a[1][ks], acc[1][ct], 0, 0, 0);
        }
    }

    // ---- epilogue: lane holds rows (node) = row_base+rt*16+r16,
    //      cols (P) = colw + ct*16 + kgrp*4 + reg  (4 consecutive) ----
    #pragma unroll
    for (int rt = 0; rt < 2; ++rt) {
        const int prow = row_base + rt * 16 + r16;
        if (prow < N_NODES) {
            ushort* rowp = Pb + (size_t)prow * P_COLS + colw + kgrp * 4;
            #pragma unroll
            for (int ct = 0; ct < 6; ++ct) {
                unsigned lo = (unsigned)f2b(acc[rt][ct][0]) |
                              ((unsigned)f2b(acc[rt][ct][1]) << 16);
                unsigned hi = (unsigned)f2b(acc[rt][ct][2]) |
                              ((unsigned)f2b(acc[rt][ct][3]) << 16);
                uint2 v; v.x = lo; v.y = hi;
                *(uint2*)(rowp + ct * 16) = v;
            }
        }
    }
}

// ---------------------------------------------------------------------------
// Kernel E: 8 LANES PER EDGE (8 edges per wave, 32 per block).
// Each lane loads one uint4 (16B); an 8-lane group consumes exactly one
// 128B cache line per load instruction. 6 P-loads in flight per lane.
//   weight = W2 . relu(Ph[0:192] + Pt[192:384] + Rb[type]) + b2
//   out = sigmoid((logit(eps) + weight) / T)
// ---------------------------------------------------------------------------
__global__ __launch_bounds__(256) void edge_kernel(
        const int* __restrict__ edge_index,
        const int* __restrict__ edge_type,
        const ushort* __restrict__ Pb,
        const float* __restrict__ Rb,
        const float* __restrict__ u,
        const float* __restrict__ W2,
        const float* __restrict__ b2,
        float* __restrict__ out) {
    const int tid  = threadIdx.x;
    const int wave = tid >> 6;
    const int lane = tid & 63;
    const int g    = lane >> 3;       // edge slot within wave, 0..7
    const int sub  = lane & 7;        // element-chunk slot, 0..7

    const int e = blockIdx.x * 32 + wave * 8 + g;   // 15625*32 == 500000 exact

    const int head = edge_index[e];
    const int tail = edge_index[N_EDGES_C + e];
    const int rel  = edge_type[e];

    const ushort* Ph = Pb + (size_t)head * P_COLS;          // cols 0:192
    const ushort* Pt = Pb + (size_t)tail * P_COLS + H_DIM;  // cols 192:384
    const int j0 = sub * 8;                                  // this lane's base elem

    // issue all 6 random-row loads up front (independent, one line per group)
    uint4 h0 = *(const uint4*)(Ph + j0);
    uint4 h1 = *(const uint4*)(Ph + j0 + 64);
    uint4 h2 = *(const uint4*)(Ph + j0 + 128);
    uint4 t0 = *(const uint4*)(Pt + j0);
    uint4 t1 = *(const uint4*)(Pt + j0 + 64);
    uint4 t2 = *(const uint4*)(Pt + j0 + 128);

    const float* Rr = Rb + rel * H_DIM + j0;   // L1-resident (24KB table)
    const float* Wp = W2 + j0;                 // L1-resident (768B)

    float acc = 0.f;
    #pragma unroll
    for (int c = 0; c < 3; ++c) {
        uint4 hv = (c == 0) ? h0 : (c == 1) ? h1 : h2;
        uint4 tv = (c == 0) ? t0 : (c == 1) ? t1 : t2;
        float4 r0 = *(const float4*)(Rr + c * 64);
        float4 r1 = *(const float4*)(Rr + c * 64 + 4);
        float4 w0 = *(const float4*)(Wp + c * 64);
        float4 w1 = *(const float4*)(Wp + c * 64 + 4);

        float h0f,h1f,h2f,h3f,h4f,h5f,h6f,h7f;
        float t0f,t1f,t2f,t3f,t4f,t5f,t6f,t7f;
        unpack2(hv.x, h0f, h1f); unpack2(hv.y, h2f, h3f);
        unpack2(hv.z, h4f, h5f); unpack2(hv.w, h6f, h7f);
        unpack2(tv.x, t0f, t1f); unpack2(tv.y, t2f, t3f);
        unpack2(tv.z, t4f, t5f); unpack2(tv.w, t6f, t7f);

        float s;
        s = fmaxf(h0f + t0f + r0.x, 0.f); acc = fmaf(s, w0.x, acc);
        s = fmaxf(h1f + t1f + r0.y, 0.f); acc = fmaf(s, w0.y, acc);
        s = fmaxf(h2f + t2f + r0.z, 0.f); acc = fmaf(s, w0.z, acc);
        s = fmaxf(h3f + t3f + r0.w, 0.f); acc = fmaf(s, w0.w, acc);
        s = fmaxf(h4f + t4f + r1.x, 0.f); acc = fmaf(s, w1.x, acc);
        s = fmaxf(h5f + t5f + r1.y, 0.f); acc = fmaf(s, w1.y, acc);
        s = fmaxf(h6f + t6f + r1.z, 0.f); acc = fmaf(s, w1.z, acc);
        s = fmaxf(h7f + t7f + r1.w, 0.f); acc = fmaf(s, w1.w, acc);
    }

    // reduce across the 8-lane group
    acc += __shfl_xor(acc, 1);
    acc += __shfl_xor(acc, 2);
    acc += __shfl_xor(acc, 4);

    if (sub == 0) {
        float weight = acc + b2[0];
        float uu  = u[e];
        float eps = fmaf(-0.9998f, uu, 0.9999f);                 // (2B-1)*u + (1-B)
        float gi  = (logf(eps) - log1pf(-eps) + weight) * 2.0f;  // / TEMPERATURE
        out[e] = 1.f / (1.f + expf(-gi));
    }
}

// ---------------------------------------------------------------------------
extern "C" void kernel_launch(void* const* d_in, const int* in_sizes, int n_in,
                              void* d_out, int out_size, void* d_ws, size_t ws_size,
                              hipStream_t stream) {
    const int*   edge_index   = (const int*)d_in[0];
    const int*   edge_type    = (const int*)d_in[1];
    const float* all_embed    = (const float*)d_in[2];
    const float* relation_emb = (const float*)d_in[3];
    const float* u            = (const float*)d_in[4];
    const float* W1           = (const float*)d_in[5];
    const float* b1           = (const float*)d_in[6];
    const float* W2           = (const float*)d_in[7];
    const float* b2           = (const float*)d_in[8];
    float*       out          = (float*)d_out;

    char* ws = (char*)d_ws;
    ushort* Bmat = (ushort*)ws;                                   // 384 x 128 bf16
    ws += (size_t)P_COLS * NODE_DIM * sizeof(ushort);
    float*  Rb   = (float*)ws;                                    // 32 x 192 f32
    ws += (size_t)N_REL * H_DIM * sizeof(float);
    ushort* Pb   = (ushort*)ws;                                   // 100000 x 384 bf16

    build_b_kernel<<<(P_COLS * NODE_DIM + 255) / 256, 256, 0, stream>>>(W1, Bmat);
    rel_precompute_kernel<<<N_REL, H_DIM, 0, stream>>>(relation_emb, W1, b1, Rb);

    dim3 gridD(N_NODES_PAD / 128, P_COLS / 192);
    node_mfma_kernel<<<gridD, 512, 0, stream>>>(all_embed, Bmat, Pb);

    edge_kernel<<<N_EDGES_C / 32, 256, 0, stream>>>(
        edge_index, edge_type, Pb, Rb, u, W2, b2, out);
}

// Round 7
// 131.565 us; speedup vs baseline: 1.1151x; 1.1151x over previous
//
#include <hip/hip_runtime.h>
#include <hip/hip_bf16.h>

#define N_NODES     100000
#define NODE_DIM    128
#define N_REL       32
#define N_EDGES_C   500000
#define H_DIM       192             // 3*MLP_DIM
#define P_COLS      384             // 2*H_DIM
#define NT          3               // row-tiles (64 rows) per block
// grid.x = ceil(1564 row-tiles / NT) = 522; 522*192 = 100224 rows covered

typedef __bf16 bf16x8 __attribute__((ext_vector_type(8)));
typedef float  f32x4  __attribute__((ext_vector_type(4)));

__device__ __forceinline__ ushort f2b(float x) {
    __hip_bfloat16 h = __float2bfloat16(x);     // RNE
    return *reinterpret_cast<ushort*>(&h);
}

__device__ __forceinline__ void unpack2(unsigned v, float& lo, float& hi) {
    union { unsigned u; float f; } a, b;
    a.u = v << 16;
    b.u = v & 0xffff0000u;
    lo = a.f; hi = b.f;
}

// ---------------------------------------------------------------------------
// Kernel B: Bmat[c][k] = bf16(Beff), c in [0,384), k in [0,128)
//   Beff[c][k] = (c < 192) ? W1[c][k] : W1[c-192][128+k]
// ---------------------------------------------------------------------------
__global__ __launch_bounds__(256) void build_b_kernel(
        const float* __restrict__ W1, ushort* __restrict__ Bmat) {
    int idx = blockIdx.x * 256 + threadIdx.x;      // 49152 total
    if (idx >= P_COLS * NODE_DIM) return;
    int c = idx >> 7, k = idx & 127;
    float v = (c < H_DIM) ? W1[(size_t)c * P_COLS + k]
                          : W1[(size_t)(c - H_DIM) * P_COLS + NODE_DIM + k];
    Bmat[idx] = f2b(v);
}

// ---------------------------------------------------------------------------
// Kernel C: Rb[r][j] = b1[j] + sum_k relation_emb[r][k] * W1[j][256+k]  (f32)
// ---------------------------------------------------------------------------
__global__ void rel_precompute_kernel(const float* __restrict__ rel,
                                      const float* __restrict__ W1,
                                      const float* __restrict__ b1,
                                      float* __restrict__ Rb) {
    int r = blockIdx.x;
    int j = threadIdx.x;           // 0..191
    const float* re = rel + r * NODE_DIM;
    const float* w  = W1 + (size_t)j * P_COLS + 2 * NODE_DIM;
    float acc = b1[j];
    #pragma unroll 8
    for (int k = 0; k < NODE_DIM; ++k)
        acc = fmaf(re[k], w[k], acc);
    Rb[r * H_DIM + j] = acc;
}

// ---------------------------------------------------------------------------
// Kernel D: MFMA GEMM, software-pipelined over NT row-tiles per block.
//   Pb[n][c] = bf16( sum_k all_embed[n][k] * Bmat[c][k] )
// Block: 256 thr = 4 waves: wr=wid>>1 (row half), wc=wid&1 (col half).
// Per iteration: block tile 64 rows x 192 cols; wave tile 32 x 96.
// B (wave's 96 cols x K=128) is loaded ONCE into 96 VGPRs before the loop;
// the vmcnt queue then carries only A-prefetch loads, so tile t+1's 16 HBM
// loads stay in flight across tile t's MFMA+epilogue (issue-early/use-late).
// Swapped-operand MFMA (verified r6): D row = P-col = kgrp*4+reg (4 consecutive
// cols per lane -> packed dwordx2 stores), D col = node row = r16.
// Row indices CLAMPED so loads are unconditional; stores guarded.
// ---------------------------------------------------------------------------
__global__ __launch_bounds__(256) void node_mfma_kernel(
        const float* __restrict__ embF,
        const ushort* __restrict__ Bmat,
        ushort* __restrict__ Pb) {
    const int tid  = threadIdx.x;
    const int wid  = tid >> 6;
    const int lane = tid & 63;
    const int r16  = lane & 15;
    const int kgrp = lane >> 4;
    const int wr   = wid >> 1;        // row half 0..1
    const int wc   = wid & 1;         // col half 0..1

    const int colw = blockIdx.y * 192 + wc * 96;

    // ---- persistent B fragments: 6 col-frags x 4 k-steps (96 VGPR) ----
    const ushort* Bbase = Bmat + (size_t)(colw + r16) * NODE_DIM + kgrp * 8;
    bf16x8 Bf[6][4];
    #pragma unroll
    for (int ct = 0; ct < 6; ++ct)
        #pragma unroll
        for (int ks = 0; ks < 4; ++ks)
            Bf[ct][ks] = *(const bf16x8*)(Bbase + (size_t)ct * 16 * NODE_DIM + ks * 32);

    const int kofs = kgrp * 8;
    int rb = blockIdx.x * (NT * 64) + wr * 32;     // wave's tile-0 row base

    // ---- prefetch tile 0: 16 independent 16B HBM loads ----
    float4 af[2][4][2];
    {
        const float* A0 = embF + (size_t)min(rb + r16,      N_NODES - 1) * NODE_DIM + kofs;
        const float* A1 = embF + (size_t)min(rb + r16 + 16, N_NODES - 1) * NODE_DIM + kofs;
        #pragma unroll
        for (int ks = 0; ks < 4; ++ks) {
            af[0][ks][0] = *(const float4*)(A0 + ks * 32);
            af[0][ks][1] = *(const float4*)(A0 + ks * 32 + 4);
            af[1][ks][0] = *(const float4*)(A1 + ks * 32);
            af[1][ks][1] = *(const float4*)(A1 + ks * 32 + 4);
        }
    }

    #pragma unroll
    for (int t = 0; t < NT; ++t) {
        // ---- convert tile t's data to bf16 frags (frees af for reuse) ----
        bf16x8 a[2][4];
        #pragma unroll
        for (int rt = 0; rt < 2; ++rt)
            #pragma unroll
            for (int ks = 0; ks < 4; ++ks) {
                float4 v0 = af[rt][ks][0];
                float4 v1 = af[rt][ks][1];
                bf16x8 r;
                r[0] = (__bf16)v0.x; r[1] = (__bf16)v0.y;
                r[2] = (__bf16)v0.z; r[3] = (__bf16)v0.w;
                r[4] = (__bf16)v1.x; r[5] = (__bf16)v1.y;
                r[6] = (__bf16)v1.z; r[7] = (__bf16)v1.w;
                a[rt][ks] = r;
            }

        // ---- issue tile t+1's loads NOW (overlap with MFMA below) ----
        if (t + 1 < NT) {
            const int rbn = rb + 64;
            const float* A0 = embF + (size_t)min(rbn + r16,      N_NODES - 1) * NODE_DIM + kofs;
            const float* A1 = embF + (size_t)min(rbn + r16 + 16, N_NODES - 1) * NODE_DIM + kofs;
            #pragma unroll
            for (int ks = 0; ks < 4; ++ks) {
                af[0][ks][0] = *(const float4*)(A0 + ks * 32);
                af[0][ks][1] = *(const float4*)(A0 + ks * 32 + 4);
                af[1][ks][0] = *(const float4*)(A1 + ks * 32);
                af[1][ks][1] = *(const float4*)(A1 + ks * 32 + 4);
            }
        }

        // ---- MFMA: operands swapped, B from persistent regs ----
        f32x4 acc[2][6] = {};
        #pragma unroll
        for (int ks = 0; ks < 4; ++ks)
            #pragma unroll
            for (int ct = 0; ct < 6; ++ct) {
                acc[0][ct] = __builtin_amdgcn_mfma_f32_16x16x32_bf16(Bf[ct][ks], a[0][ks], acc[0][ct], 0, 0, 0);
                acc[1][ct] = __builtin_amdgcn_mfma_f32_16x16x32_bf16(Bf[ct][ks], a[1][ks], acc[1][ct], 0, 0, 0);
            }

        // ---- epilogue: packed dwordx2 stores, 4 consecutive P-cols/lane ----
        #pragma unroll
        for (int rt = 0; rt < 2; ++rt) {
            const int prow = rb + rt * 16 + r16;
            if (prow < N_NODES) {
                ushort* rowp = Pb + (size_t)prow * P_COLS + colw + kgrp * 4;
                #pragma unroll
                for (int ct = 0; ct < 6; ++ct) {
                    unsigned lo = (unsigned)f2b(acc[rt][ct][0]) |
                                  ((unsigned)f2b(acc[rt][ct][1]) << 16);
                    unsigned hi = (unsigned)f2b(acc[rt][ct][2]) |
                                  ((unsigned)f2b(acc[rt][ct][3]) << 16);
                    uint2 v; v.x = lo; v.y = hi;
                    *(uint2*)(rowp + ct * 16) = v;
                }
            }
        }

        rb += 64;
    }
}

// ---------------------------------------------------------------------------
// Kernel E: 8 LANES PER EDGE (8 edges per wave, 32 per block).
// Each lane loads one uint4 (16B); an 8-lane group consumes exactly one
// 128B cache line per load instruction. 6 P-loads in flight per lane.
//   weight = W2 . relu(Ph[0:192] + Pt[192:384] + Rb[type]) + b2
//   out = sigmoid((logit(eps) + weight) / T)
// ---------------------------------------------------------------------------
__global__ __launch_bounds__(256) void edge_kernel(
        const int* __restrict__ edge_index,
        const int* __restrict__ edge_type,
        const ushort* __restrict__ Pb,
        const float* __restrict__ Rb,
        const float* __restrict__ u,
        const float* __restrict__ W2,
        const float* __restrict__ b2,
        float* __restrict__ out) {
    const int tid  = threadIdx.x;
    const int wave = tid >> 6;
    const int lane = tid & 63;
    const int g    = lane >> 3;       // edge slot within wave, 0..7
    const int sub  = lane & 7;        // element-chunk slot, 0..7

    const int e = blockIdx.x * 32 + wave * 8 + g;   // 15625*32 == 500000 exact

    const int head = edge_index[e];
    const int tail = edge_index[N_EDGES_C + e];
    const int rel  = edge_type[e];

    const ushort* Ph = Pb + (size_t)head * P_COLS;          // cols 0:192
    const ushort* Pt = Pb + (size_t)tail * P_COLS + H_DIM;  // cols 192:384
    const int j0 = sub * 8;                                  // this lane's base elem

    // issue all 6 random-row loads up front (independent, one line per group)
    uint4 h0 = *(const uint4*)(Ph + j0);
    uint4 h1 = *(const uint4*)(Ph + j0 + 64);
    uint4 h2 = *(const uint4*)(Ph + j0 + 128);
    uint4 t0 = *(const uint4*)(Pt + j0);
    uint4 t1 = *(const uint4*)(Pt + j0 + 64);
    uint4 t2 = *(const uint4*)(Pt + j0 + 128);

    const float* Rr = Rb + rel * H_DIM + j0;   // L1-resident (24KB table)
    const float* Wp = W2 + j0;                 // L1-resident (768B)

    float acc = 0.f;
    #pragma unroll
    for (int c = 0; c < 3; ++c) {
        uint4 hv = (c == 0) ? h0 : (c == 1) ? h1 : h2;
        uint4 tv = (c == 0) ? t0 : (c == 1) ? t1 : t2;
        float4 r0 = *(const float4*)(Rr + c * 64);
        float4 r1 = *(const float4*)(Rr + c * 64 + 4);
        float4 w0 = *(const float4*)(Wp + c * 64);
        float4 w1 = *(const float4*)(Wp + c * 64 + 4);

        float h0f,h1f,h2f,h3f,h4f,h5f,h6f,h7f;
        float t0f,t1f,t2f,t3f,t4f,t5f,t6f,t7f;
        unpack2(hv.x, h0f, h1f); unpack2(hv.y, h2f, h3f);
        unpack2(hv.z, h4f, h5f); unpack2(hv.w, h6f, h7f);
        unpack2(tv.x, t0f, t1f); unpack2(tv.y, t2f, t3f);
        unpack2(tv.z, t4f, t5f); unpack2(tv.w, t6f, t7f);

        float s;
        s = fmaxf(h0f + t0f + r0.x, 0.f); acc = fmaf(s, w0.x, acc);
        s = fmaxf(h1f + t1f + r0.y, 0.f); acc = fmaf(s, w0.y, acc);
        s = fmaxf(h2f + t2f + r0.z, 0.f); acc = fmaf(s, w0.z, acc);
        s = fmaxf(h3f + t3f + r0.w, 0.f); acc = fmaf(s, w0.w, acc);
        s = fmaxf(h4f + t4f + r1.x, 0.f); acc = fmaf(s, w1.x, acc);
        s = fmaxf(h5f + t5f + r1.y, 0.f); acc = fmaf(s, w1.y, acc);
        s = fmaxf(h6f + t6f + r1.z, 0.f); acc = fmaf(s, w1.z, acc);
        s = fmaxf(h7f + t7f + r1.w, 0.f); acc = fmaf(s, w1.w, acc);
    }

    // reduce across the 8-lane group
    acc += __shfl_xor(acc, 1);
    acc += __shfl_xor(acc, 2);
    acc += __shfl_xor(acc, 4);

    if (sub == 0) {
        float weight = acc + b2[0];
        float uu  = u[e];
        float eps = fmaf(-0.9998f, uu, 0.9999f);                 // (2B-1)*u + (1-B)
        float gi  = (logf(eps) - log1pf(-eps) + weight) * 2.0f;  // / TEMPERATURE
        out[e] = 1.f / (1.f + expf(-gi));
    }
}

// ---------------------------------------------------------------------------
extern "C" void kernel_launch(void* const* d_in, const int* in_sizes, int n_in,
                              void* d_out, int out_size, void* d_ws, size_t ws_size,
                              hipStream_t stream) {
    const int*   edge_index   = (const int*)d_in[0];
    const int*   edge_type    = (const int*)d_in[1];
    const float* all_embed    = (const float*)d_in[2];
    const float* relation_emb = (const float*)d_in[3];
    const float* u            = (const float*)d_in[4];
    const float* W1           = (const float*)d_in[5];
    const float* b1           = (const float*)d_in[6];
    const float* W2           = (const float*)d_in[7];
    const float* b2           = (const float*)d_in[8];
    float*       out          = (float*)d_out;

    char* ws = (char*)d_ws;
    ushort* Bmat = (ushort*)ws;                                   // 384 x 128 bf16
    ws += (size_t)P_COLS * NODE_DIM * sizeof(ushort);
    float*  Rb   = (float*)ws;                                    // 32 x 192 f32
    ws += (size_t)N_REL * H_DIM * sizeof(float);
    ushort* Pb   = (ushort*)ws;                                   // 100000 x 384 bf16

    build_b_kernel<<<(P_COLS * NODE_DIM + 255) / 256, 256, 0, stream>>>(W1, Bmat);
    rel_precompute_kernel<<<N_REL, H_DIM, 0, stream>>>(relation_emb, W1, b1, Rb);

    // 1564 row-tiles of 64 rows; NT per block -> grid.x = 522
    dim3 gridD((1564 + NT - 1) / NT, 2);
    node_mfma_kernel<<<gridD, 256, 0, stream>>>(all_embed, Bmat, Pb);

    edge_kernel<<<N_EDGES_C / 32, 256, 0, stream>>>(
        edge_index, edge_type, Pb, Rb, u, W2, b2, out);
}

// Round 8
// 116.864 us; speedup vs baseline: 1.2554x; 1.1258x over previous
//
#include <hip/hip_runtime.h>
#include <hip/hip_bf16.h>

#define N_NODES     100000
#define NODE_DIM    128
#define N_REL       32
#define N_EDGES_C   500000
#define H_DIM       192             // 3*MLP_DIM
#define P_COLS      384             // 2*H_DIM
#define TILE_ROWS   64
#define NTILES      1563            // ceil(100000/64)
#define NBLK        256             // one persistent-style block per CU

typedef __bf16 bf16x8 __attribute__((ext_vector_type(8)));
typedef float  f32x4  __attribute__((ext_vector_type(4)));
typedef unsigned int u32;

__device__ __forceinline__ ushort f2b(float x) {
    __hip_bfloat16 h = __float2bfloat16(x);     // RNE
    return *reinterpret_cast<ushort*>(&h);
}

__device__ __forceinline__ void unpack2(unsigned v, float& lo, float& hi) {
    union { unsigned u; float f; } a, b;
    a.u = v << 16;
    b.u = v & 0xffff0000u;
    lo = a.f; hi = b.f;
}

// async global->LDS, 16B per lane (dest = wave-uniform base + lane*16)
__device__ __forceinline__ void gload_lds16(const void* g, void* l) {
    __builtin_amdgcn_global_load_lds(
        (const __attribute__((address_space(1))) u32*)g,
        (__attribute__((address_space(3))) u32*)l, 16, 0, 0);
}

// ---------------------------------------------------------------------------
// Kernel B: Bmat[c][k] = bf16(Beff), c in [0,384), k in [0,128)
//   Beff[c][k] = (c < 192) ? W1[c][k] : W1[c-192][128+k]
// ---------------------------------------------------------------------------
__global__ __launch_bounds__(256) void build_b_kernel(
        const float* __restrict__ W1, ushort* __restrict__ Bmat) {
    int idx = blockIdx.x * 256 + threadIdx.x;      // 49152 total
    if (idx >= P_COLS * NODE_DIM) return;
    int c = idx >> 7, k = idx & 127;
    float v = (c < H_DIM) ? W1[(size_t)c * P_COLS + k]
                          : W1[(size_t)(c - H_DIM) * P_COLS + NODE_DIM + k];
    Bmat[idx] = f2b(v);
}

// ---------------------------------------------------------------------------
// Kernel C: Rb[r][j] = b1[j] + sum_k relation_emb[r][k] * W1[j][256+k]  (f32)
// ---------------------------------------------------------------------------
__global__ void rel_precompute_kernel(const float* __restrict__ rel,
                                      const float* __restrict__ W1,
                                      const float* __restrict__ b1,
                                      float* __restrict__ Rb) {
    int r = blockIdx.x;
    int j = threadIdx.x;           // 0..191
    const float* re = rel + r * NODE_DIM;
    const float* w  = W1 + (size_t)j * P_COLS + 2 * NODE_DIM;
    float acc = b1[j];
    #pragma unroll 8
    for (int k = 0; k < NODE_DIM; ++k)
        acc = fmaf(re[k], w[k], acc);
    Rb[r * H_DIM + j] = acc;
}

// ---------------------------------------------------------------------------
// Kernel D: MFMA GEMM with async LDS staging (global_load_lds, width 16),
// double-buffered 64-row f32 A-tiles, persistent blocks (NBLK=256, 1/CU).
//   Pb[n][c] = bf16( sum_k all_embed[n][k] * Bmat[c][k] )
// Block: 512 thr = 8 waves: wr=wid&1 (32-row half), wc=wid>>1 (96-col quarter).
// B (wave's 96 cols x K=128) persistent in 96 VGPRs, loaded once from L2.
// LDS A layout XOR-swizzled at 32B-granule granularity (g ^= row&15), applied
// on BOTH sides: pre-swizzled per-lane GLOBAL source (LDS dest stays linear,
// required by global_load_lds) and the same XOR on the ds_read address.
// Swapped-operand MFMA (verified r6/r7): D row = P-col = kgrp*4+reg (4
// consecutive cols/lane -> packed dwordx2 stores), D col = node row = r16.
// Loop: __syncthreads (drains vmcnt => buf[p] ready) -> issue stage(p^1,t+NBLK)
// -> compute tile t from buf[p]. Prefetch flies under compute.
// ---------------------------------------------------------------------------
__global__ __launch_bounds__(512) void node_mfma_kernel(
        const float* __restrict__ embF,
        const ushort* __restrict__ Bmat,
        ushort* __restrict__ Pb) {
    __shared__ float ldsA[2][TILE_ROWS * NODE_DIM];   // 2 x 32 KB

    const int tid  = threadIdx.x;
    const int wid  = tid >> 6;
    const int lane = tid & 63;
    const int r16  = lane & 15;
    const int kgrp = lane >> 4;
    const int wr   = wid & 1;        // row half (32 rows)
    const int wc   = wid >> 1;       // col quarter (96 cols)
    const int colw = wc * 96;

    // ---- persistent B fragments: 6 col-frags x 4 k-steps (96 VGPR) ----
    bf16x8 Bf[6][4];
    {
        const ushort* Bbase = Bmat + (size_t)(colw + r16) * NODE_DIM + kgrp * 8;
        #pragma unroll
        for (int ct = 0; ct < 6; ++ct)
            #pragma unroll
            for (int ks = 0; ks < 4; ++ks)
                Bf[ct][ks] = *(const bf16x8*)(Bbase + (size_t)ct * 16 * NODE_DIM + ks * 32);
    }

    const size_t A_CLAMP = (size_t)N_NODES * NODE_DIM * sizeof(float) - 16;

    // stage one 64x128 f32 tile into buf p: 4 x 16B async loads per thread.
    // LDS linear offset L; source granule pre-swizzled: g_src = g ^ (row&15).
    auto stage = [&](int p, int tile) {
        const size_t tbase = (size_t)tile * (TILE_ROWS * NODE_DIM * 4);
        #pragma unroll
        for (int i = 0; i < 4; ++i) {
            const int L    = i * 8192 + tid * 16;     // 0..32752
            const int rowl = L >> 9;                  // 0..63
            const int g    = (L >> 5) & 15;           // 32B granule in row
            const int h16  = L & 16;                  // 16B half of granule
            size_t src = tbase +
                (size_t)((rowl << 9) | ((g ^ (rowl & 15)) << 5) | h16);
            if (src > A_CLAMP) src = A_CLAMP;         // pad rows: garbage, guarded
            gload_lds16((const char*)embF + src, (char*)&ldsA[p][0] + L);
        }
    };

    int tile = blockIdx.x;
    stage(0, tile);
    int p = 0;

    for (; tile < NTILES; tile += NBLK) {
        __syncthreads();               // vmcnt(0)+barrier: buf[p] staged & visible

        if (tile + NBLK < NTILES)
            stage(p ^ 1, tile + NBLK); // async prefetch under compute

        // ---- A fragments from LDS (inverse granule swizzle on read) ----
        bf16x8 a[2][4];
        #pragma unroll
        for (int rt = 0; rt < 2; ++rt) {
            const int rowl  = wr * 32 + rt * 16 + r16;
            const int rbase = rowl * NODE_DIM;
            const int sw    = rowl & 15;
            #pragma unroll
            for (int ks = 0; ks < 4; ++ks) {
                const int gl = (kgrp + ks * 4) ^ sw;          // lds granule
                const float* pf = &ldsA[p][rbase + gl * 8];
                float4 v0 = *(const float4*)pf;
                float4 v1 = *(const float4*)(pf + 4);
                bf16x8 r;
                r[0] = (__bf16)v0.x; r[1] = (__bf16)v0.y;
                r[2] = (__bf16)v0.z; r[3] = (__bf16)v0.w;
                r[4] = (__bf16)v1.x; r[5] = (__bf16)v1.y;
                r[6] = (__bf16)v1.z; r[7] = (__bf16)v1.w;
                a[rt][ks] = r;
            }
        }

        // ---- MFMA: operands swapped, B from persistent regs ----
        f32x4 acc[2][6] = {};
        #pragma unroll
        for (int ks = 0; ks < 4; ++ks)
            #pragma unroll
            for (int ct = 0; ct < 6; ++ct) {
                acc[0][ct] = __builtin_amdgcn_mfma_f32_16x16x32_bf16(Bf[ct][ks], a[0][ks], acc[0][ct], 0, 0, 0);
                acc[1][ct] = __builtin_amdgcn_mfma_f32_16x16x32_bf16(Bf[ct][ks], a[1][ks], acc[1][ct], 0, 0, 0);
            }

        // ---- epilogue: packed dwordx2 stores, 4 consecutive P-cols/lane ----
        const int rowbase = tile * TILE_ROWS + wr * 32;
        #pragma unroll
        for (int rt = 0; rt < 2; ++rt) {
            const int prow = rowbase + rt * 16 + r16;
            if (prow < N_NODES) {
                ushort* rowp = Pb + (size_t)prow * P_COLS + colw + kgrp * 4;
                #pragma unroll
                for (int ct = 0; ct < 6; ++ct) {
                    unsigned lo = (unsigned)f2b(acc[rt][ct][0]) |
                                  ((unsigned)f2b(acc[rt][ct][1]) << 16);
                    unsigned hi = (unsigned)f2b(acc[rt][ct][2]) |
                                  ((unsigned)f2b(acc[rt][ct][3]) << 16);
                    uint2 v; v.x = lo; v.y = hi;
                    *(uint2*)(rowp + ct * 16) = v;
                }
            }
        }

        p ^= 1;
    }
}

// ---------------------------------------------------------------------------
// Kernel E: 8 LANES PER EDGE (8 edges per wave, 32 per block).
// Each lane loads one uint4 (16B); an 8-lane group consumes exactly one
// 128B cache line per load instruction. 6 P-loads in flight per lane.
//   weight = W2 . relu(Ph[0:192] + Pt[192:384] + Rb[type]) + b2
//   out = sigmoid((logit(eps) + weight) / T)
// ---------------------------------------------------------------------------
__global__ __launch_bounds__(256) void edge_kernel(
        const int* __restrict__ edge_index,
        const int* __restrict__ edge_type,
        const ushort* __restrict__ Pb,
        const float* __restrict__ Rb,
        const float* __restrict__ u,
        const float* __restrict__ W2,
        const float* __restrict__ b2,
        float* __restrict__ out) {
    const int tid  = threadIdx.x;
    const int wave = tid >> 6;
    const int lane = tid & 63;
    const int g    = lane >> 3;       // edge slot within wave, 0..7
    const int sub  = lane & 7;        // element-chunk slot, 0..7

    const int e = blockIdx.x * 32 + wave * 8 + g;   // 15625*32 == 500000 exact

    const int head = edge_index[e];
    const int tail = edge_index[N_EDGES_C + e];
    const int rel  = edge_type[e];

    const ushort* Ph = Pb + (size_t)head * P_COLS;          // cols 0:192
    const ushort* Pt = Pb + (size_t)tail * P_COLS + H_DIM;  // cols 192:384
    const int j0 = sub * 8;                                  // this lane's base elem

    // issue all 6 random-row loads up front (independent, one line per group)
    uint4 h0 = *(const uint4*)(Ph + j0);
    uint4 h1 = *(const uint4*)(Ph + j0 + 64);
    uint4 h2 = *(const uint4*)(Ph + j0 + 128);
    uint4 t0 = *(const uint4*)(Pt + j0);
    uint4 t1 = *(const uint4*)(Pt + j0 + 64);
    uint4 t2 = *(const uint4*)(Pt + j0 + 128);

    const float* Rr = Rb + rel * H_DIM + j0;   // L1-resident (24KB table)
    const float* Wp = W2 + j0;                 // L1-resident (768B)

    float acc = 0.f;
    #pragma unroll
    for (int c = 0; c < 3; ++c) {
        uint4 hv = (c == 0) ? h0 : (c == 1) ? h1 : h2;
        uint4 tv = (c == 0) ? t0 : (c == 1) ? t1 : t2;
        float4 r0 = *(const float4*)(Rr + c * 64);
        float4 r1 = *(const float4*)(Rr + c * 64 + 4);
        float4 w0 = *(const float4*)(Wp + c * 64);
        float4 w1 = *(const float4*)(Wp + c * 64 + 4);

        float h0f,h1f,h2f,h3f,h4f,h5f,h6f,h7f;
        float t0f,t1f,t2f,t3f,t4f,t5f,t6f,t7f;
        unpack2(hv.x, h0f, h1f); unpack2(hv.y, h2f, h3f);
        unpack2(hv.z, h4f, h5f); unpack2(hv.w, h6f, h7f);
        unpack2(tv.x, t0f, t1f); unpack2(tv.y, t2f, t3f);
        unpack2(tv.z, t4f, t5f); unpack2(tv.w, t6f, t7f);

        float s;
        s = fmaxf(h0f + t0f + r0.x, 0.f); acc = fmaf(s, w0.x, acc);
        s = fmaxf(h1f + t1f + r0.y, 0.f); acc = fmaf(s, w0.y, acc);
        s = fmaxf(h2f + t2f + r0.z, 0.f); acc = fmaf(s, w0.z, acc);
        s = fmaxf(h3f + t3f + r0.w, 0.f); acc = fmaf(s, w0.w, acc);
        s = fmaxf(h4f + t4f + r1.x, 0.f); acc = fmaf(s, w1.x, acc);
        s = fmaxf(h5f + t5f + r1.y, 0.f); acc = fmaf(s, w1.y, acc);
        s = fmaxf(h6f + t6f + r1.z, 0.f); acc = fmaf(s, w1.z, acc);
        s = fmaxf(h7f + t7f + r1.w, 0.f); acc = fmaf(s, w1.w, acc);
    }

    // reduce across the 8-lane group
    acc += __shfl_xor(acc, 1);
    acc += __shfl_xor(acc, 2);
    acc += __shfl_xor(acc, 4);

    if (sub == 0) {
        float weight = acc + b2[0];
        float uu  = u[e];
        float eps = fmaf(-0.9998f, uu, 0.9999f);                 // (2B-1)*u + (1-B)
        float gi  = (logf(eps) - log1pf(-eps) + weight) * 2.0f;  // / TEMPERATURE
        out[e] = 1.f / (1.f + expf(-gi));
    }
}

// ---------------------------------------------------------------------------
extern "C" void kernel_launch(void* const* d_in, const int* in_sizes, int n_in,
                              void* d_out, int out_size, void* d_ws, size_t ws_size,
                              hipStream_t stream) {
    const int*   edge_index   = (const int*)d_in[0];
    const int*   edge_type    = (const int*)d_in[1];
    const float* all_embed    = (const float*)d_in[2];
    const float* relation_emb = (const float*)d_in[3];
    const float* u            = (const float*)d_in[4];
    const float* W1           = (const float*)d_in[5];
    const float* b1           = (const float*)d_in[6];
    const float* W2           = (const float*)d_in[7];
    const float* b2           = (const float*)d_in[8];
    float*       out          = (float*)d_out;

    char* ws = (char*)d_ws;
    ushort* Bmat = (ushort*)ws;                                   // 384 x 128 bf16
    ws += (size_t)P_COLS * NODE_DIM * sizeof(ushort);
    float*  Rb   = (float*)ws;                                    // 32 x 192 f32
    ws += (size_t)N_REL * H_DIM * sizeof(float);
    ushort* Pb   = (ushort*)ws;                                   // 100000 x 384 bf16

    build_b_kernel<<<(P_COLS * NODE_DIM + 255) / 256, 256, 0, stream>>>(W1, Bmat);
    rel_precompute_kernel<<<N_REL, H_DIM, 0, stream>>>(relation_emb, W1, b1, Rb);

    node_mfma_kernel<<<NBLK, 512, 0, stream>>>(all_embed, Bmat, Pb);

    edge_kernel<<<N_EDGES_C / 32, 256, 0, stream>>>(
        edge_index, edge_type, Pb, Rb, u, W2, b2, out);
}

// Round 9
// 102.204 us; speedup vs baseline: 1.4355x; 1.1434x over previous
//
#include <hip/hip_runtime.h>
#include <hip/hip_bf16.h>

#define N_NODES     100000
#define NODE_DIM    128
#define N_REL       32
#define N_EDGES_C   500000
#define H_DIM       192             // 3*MLP_DIM
#define P_COLS      384             // 2*H_DIM
#define TILE_ROWS   32
#define NTILES      3125            // ceil(100000/32)
#define NBLK        512             // 2 blocks per CU

typedef __bf16 bf16x8 __attribute__((ext_vector_type(8)));
typedef float  f32x4  __attribute__((ext_vector_type(4)));
typedef float  f32x2  __attribute__((ext_vector_type(2)));
typedef unsigned int u32;

__device__ __forceinline__ ushort f2b(float x) {
    __hip_bfloat16 h = __float2bfloat16(x);     // RNE
    return *reinterpret_cast<ushort*>(&h);
}

// async global->LDS, 16B per lane (dest = wave-uniform base + lane*16)
__device__ __forceinline__ void gload_lds16(const void* g, void* l) {
    __builtin_amdgcn_global_load_lds(
        (const __attribute__((address_space(1))) u32*)g,
        (__attribute__((address_space(3))) u32*)l, 16, 0, 0);
}

// ---------------------------------------------------------------------------
// Kernel B: Bmat[c][k] = bf16(Beff), c in [0,384), k in [0,128)
// ---------------------------------------------------------------------------
__global__ __launch_bounds__(256) void build_b_kernel(
        const float* __restrict__ W1, ushort* __restrict__ Bmat) {
    int idx = blockIdx.x * 256 + threadIdx.x;      // 49152 total
    if (idx >= P_COLS * NODE_DIM) return;
    int c = idx >> 7, k = idx & 127;
    float v = (c < H_DIM) ? W1[(size_t)c * P_COLS + k]
                          : W1[(size_t)(c - H_DIM) * P_COLS + NODE_DIM + k];
    Bmat[idx] = f2b(v);
}

// ---------------------------------------------------------------------------
// Kernel C: Rb[r][j] = b1[j] + sum_k relation_emb[r][k] * W1[j][256+k]  (f32)
// ---------------------------------------------------------------------------
__global__ void rel_precompute_kernel(const float* __restrict__ rel,
                                      const float* __restrict__ W1,
                                      const float* __restrict__ b1,
                                      float* __restrict__ Rb) {
    int r = blockIdx.x;
    int j = threadIdx.x;           // 0..191
    const float* re = rel + r * NODE_DIM;
    const float* w  = W1 + (size_t)j * P_COLS + 2 * NODE_DIM;
    float acc = b1[j];
    #pragma unroll 8
    for (int k = 0; k < NODE_DIM; ++k)
        acc = fmaf(re[k], w[k], acc);
    Rb[r * H_DIM + j] = acc;
}

// ---------------------------------------------------------------------------
// Kernel D: MFMA GEMM, async LDS staging, 3-buffer depth-2 pipeline with
// COUNTED vmcnt (never 0 mid-loop) so one tile of loads stays in flight
// across the barrier (T3/T4).  512 blocks (2/CU), 256 thr = 4 waves.
// Per tile: 32 rows x 384 cols; wave = 32 rows x 96 cols (wc = wid).
// B (wave's 96 cols x K=128) persistent in 96 VGPRs.
// LDS swizzle at 16B granule: g16 ^= (row&31), applied on the pre-swizzled
// GLOBAL source (LDS dest linear, required by global_load_lds) and on the
// ds_read address -> b128 reads spread over all 8 bank-groups (conflict-free).
// Swapped-operand MFMA: D row = P-col = kgrp*4+reg (4 consecutive cols/lane
// -> packed dwordx2 stores), D col = node row = r16.
// ---------------------------------------------------------------------------
__global__ __launch_bounds__(256) void node_mfma_kernel(
        const float* __restrict__ embF,
        const ushort* __restrict__ Bmat,
        ushort* __restrict__ Pb) {
    __shared__ float ldsA[3][TILE_ROWS * NODE_DIM];   // 3 x 16 KB

    const int tid  = threadIdx.x;
    const int wid  = tid >> 6;
    const int lane = tid & 63;
    const int r16  = lane & 15;
    const int kgrp = lane >> 4;
    const int colw = wid * 96;

    // ---- persistent B fragments: 6 col-frags x 4 k-steps (96 VGPR) ----
    bf16x8 Bf[6][4];
    {
        const ushort* Bbase = Bmat + (size_t)(colw + r16) * NODE_DIM + kgrp * 8;
        #pragma unroll
        for (int ct = 0; ct < 6; ++ct)
            #pragma unroll
            for (int ks = 0; ks < 4; ++ks)
                Bf[ct][ks] = *(const bf16x8*)(Bbase + (size_t)ct * 16 * NODE_DIM + ks * 32);
    }

    const size_t A_CLAMP = (size_t)N_NODES * NODE_DIM * sizeof(float) - 16;

    // stage one 32x128 f32 tile into buf p: 4 x 16B async loads per thread.
    // LDS linear offset; global source 16B-granule pre-swizzled.
    auto stage = [&](int p, int tile) {
        const size_t tbase = (size_t)tile * (TILE_ROWS * NODE_DIM * 4);
        #pragma unroll
        for (int i = 0; i < 4; ++i) {
            const int L    = i * 4096 + tid * 16;     // 0..16368
            const int u16  = L >> 4;                  // 16B unit 0..1023
            const int rowl = u16 >> 5;                // 0..31
            const int g16  = u16 & 31;                // 16B granule in row
            size_t src = tbase +
                (size_t)((rowl << 9) | ((g16 ^ rowl) << 4));
            if (src > A_CLAMP) src = A_CLAMP;         // pad rows: garbage, guarded
            gload_lds16((const char*)embF + src, (char*)&ldsA[p][0] + L);
        }
    };

    int tile = blockIdx.x;
    stage(0, tile);
    if (tile + NBLK < NTILES) stage(1, tile + NBLK);
    int p = 0;

    for (; tile < NTILES; tile += NBLK) {
        const bool more1 = (tile + NBLK)     < NTILES;
        const bool more2 = (tile + 2 * NBLK) < NTILES;

        // wait for buf[p] only: keep the newer tile's 4 loads in flight
        if (more1) asm volatile("s_waitcnt vmcnt(4)" ::: "memory");
        else       asm volatile("s_waitcnt vmcnt(0)" ::: "memory");
        __builtin_amdgcn_s_barrier();

        if (more2) stage((p + 2) % 3, tile + 2 * NBLK);   // depth-2 prefetch

        // ---- A fragments from LDS (matching 16B-granule swizzle) ----
        bf16x8 a[2][4];
        #pragma unroll
        for (int rt = 0; rt < 2; ++rt) {
            const int rowl = rt * 16 + r16;           // 0..31
            #pragma unroll
            for (int ks = 0; ks < 4; ++ks) {
                const int gbase = 2 * (kgrp + ks * 4);
                const float* pa = &ldsA[p][rowl * NODE_DIM + ((gbase    ) ^ rowl) * 4];
                const float* pb = &ldsA[p][rowl * NODE_DIM + ((gbase + 1) ^ rowl) * 4];
                float4 v0 = *(const float4*)pa;
                float4 v1 = *(const float4*)pb;
                bf16x8 r;
                r[0] = (__bf16)v0.x; r[1] = (__bf16)v0.y;
                r[2] = (__bf16)v0.z; r[3] = (__bf16)v0.w;
                r[4] = (__bf16)v1.x; r[5] = (__bf16)v1.y;
                r[6] = (__bf16)v1.z; r[7] = (__bf16)v1.w;
                a[rt][ks] = r;
            }
        }

        // ---- MFMA: operands swapped, B from persistent regs ----
        f32x4 acc[2][6] = {};
        #pragma unroll
        for (int ks = 0; ks < 4; ++ks)
            #pragma unroll
            for (int ct = 0; ct < 6; ++ct) {
                acc[0][ct] = __builtin_amdgcn_mfma_f32_16x16x32_bf16(Bf[ct][ks], a[0][ks], acc[0][ct], 0, 0, 0);
                acc[1][ct] = __builtin_amdgcn_mfma_f32_16x16x32_bf16(Bf[ct][ks], a[1][ks], acc[1][ct], 0, 0, 0);
            }

        // ---- epilogue: packed dwordx2 stores, 4 consecutive P-cols/lane ----
        const int rowbase = tile * TILE_ROWS;
        #pragma unroll
        for (int rt = 0; rt < 2; ++rt) {
            const int prow = rowbase + rt * 16 + r16;
            if (prow < N_NODES) {
                ushort* rowp = Pb + (size_t)prow * P_COLS + colw + kgrp * 4;
                #pragma unroll
                for (int ct = 0; ct < 6; ++ct) {
                    unsigned lo = (unsigned)f2b(acc[rt][ct][0]) |
                                  ((unsigned)f2b(acc[rt][ct][1]) << 16);
                    unsigned hi = (unsigned)f2b(acc[rt][ct][2]) |
                                  ((unsigned)f2b(acc[rt][ct][3]) << 16);
                    uint2 v; v.x = lo; v.y = hi;
                    *(uint2*)(rowp + ct * 16) = v;
                }
            }
        }

        p = (p + 1) % 3;
    }
}

// ---------------------------------------------------------------------------
// Kernel E: 8 LANES PER EDGE, packed f32x2 math (v_pk_add/max/fma).
//   weight = W2 . relu(Ph[0:192] + Pt[192:384] + Rb[type]) + b2
//   out = sigmoid((logit(eps) + weight) / T)
// ---------------------------------------------------------------------------
__device__ __forceinline__ void pairproc(unsigned h, unsigned t,
                                         f32x2 r, f32x2 w, f32x2& acc) {
    union { unsigned u[2]; f32x2 f; } A, B;
    A.u[0] = h << 16;          A.u[1] = h & 0xffff0000u;
    B.u[0] = t << 16;          B.u[1] = t & 0xffff0000u;
    f32x2 s = A.f + B.f + r;
#if __has_builtin(__builtin_elementwise_max)
    s = __builtin_elementwise_max(s, (f32x2)(0.f));
#else
    s[0] = fmaxf(s[0], 0.f); s[1] = fmaxf(s[1], 0.f);
#endif
    acc += s * w;              // fp-contract -> v_pk_fma_f32
}

__global__ __launch_bounds__(256) void edge_kernel(
        const int* __restrict__ edge_index,
        const int* __restrict__ edge_type,
        const ushort* __restrict__ Pb,
        const float* __restrict__ Rb,
        const float* __restrict__ u,
        const float* __restrict__ W2,
        const float* __restrict__ b2,
        float* __restrict__ out) {
    const int tid  = threadIdx.x;
    const int wave = tid >> 6;
    const int lane = tid & 63;
    const int g    = lane >> 3;       // edge slot within wave, 0..7
    const int sub  = lane & 7;        // element-chunk slot, 0..7

    const int e = blockIdx.x * 32 + wave * 8 + g;   // 15625*32 == 500000 exact

    const int head = edge_index[e];
    const int tail = edge_index[N_EDGES_C + e];
    const int rel  = edge_type[e];

    const ushort* Ph = Pb + (size_t)head * P_COLS;          // cols 0:192
    const ushort* Pt = Pb + (size_t)tail * P_COLS + H_DIM;  // cols 192:384
    const int j0 = sub * 8;                                  // this lane's base elem

    // issue all 6 random-row loads up front (independent, one line per group)
    uint4 h0 = *(const uint4*)(Ph + j0);
    uint4 h1 = *(const uint4*)(Ph + j0 + 64);
    uint4 h2 = *(const uint4*)(Ph + j0 + 128);
    uint4 t0 = *(const uint4*)(Pt + j0);
    uint4 t1 = *(const uint4*)(Pt + j0 + 64);
    uint4 t2 = *(const uint4*)(Pt + j0 + 128);

    const float* Rr = Rb + rel * H_DIM + j0;   // L1-resident (24KB table)
    const float* Wp = W2 + j0;                 // L1-resident (768B)

    f32x2 acc2 = {0.f, 0.f};
    #pragma unroll
    for (int c = 0; c < 3; ++c) {
        uint4 hv = (c == 0) ? h0 : (c == 1) ? h1 : h2;
        uint4 tv = (c == 0) ? t0 : (c == 1) ? t1 : t2;
        f32x4 r4a = *(const f32x4*)(Rr + c * 64);
        f32x4 r4b = *(const f32x4*)(Rr + c * 64 + 4);
        f32x4 w4a = *(const f32x4*)(Wp + c * 64);
        f32x4 w4b = *(const f32x4*)(Wp + c * 64 + 4);

        pairproc(hv.x, tv.x, r4a.xy, w4a.xy, acc2);
        pairproc(hv.y, tv.y, r4a.zw, w4a.zw, acc2);
        pairproc(hv.z, tv.z, r4b.xy, w4b.xy, acc2);
        pairproc(hv.w, tv.w, r4b.zw, w4b.zw, acc2);
    }

    float acc = acc2[0] + acc2[1];
    acc += __shfl_xor(acc, 1);
    acc += __shfl_xor(acc, 2);
    acc += __shfl_xor(acc, 4);

    if (sub == 0) {
        float weight = acc + b2[0];
        float uu  = u[e];
        float eps = fmaf(-0.9998f, uu, 0.9999f);                 // (2B-1)*u + (1-B)
        float gi  = (logf(eps) - log1pf(-eps) + weight) * 2.0f;  // / TEMPERATURE
        out[e] = 1.f / (1.f + expf(-gi));
    }
}

// ---------------------------------------------------------------------------
extern "C" void kernel_launch(void* const* d_in, const int* in_sizes, int n_in,
                              void* d_out, int out_size, void* d_ws, size_t ws_size,
                              hipStream_t stream) {
    const int*   edge_index   = (const int*)d_in[0];
    const int*   edge_type    = (const int*)d_in[1];
    const float* all_embed    = (const float*)d_in[2];
    const float* relation_emb = (const float*)d_in[3];
    const float* u            = (const float*)d_in[4];
    const float* W1           = (const float*)d_in[5];
    const float* b1           = (const float*)d_in[6];
    const float* W2           = (const float*)d_in[7];
    const float* b2           = (const float*)d_in[8];
    float*       out          = (float*)d_out;

    char* ws = (char*)d_ws;
    ushort* Bmat = (ushort*)ws;                                   // 384 x 128 bf16
    ws += (size_t)P_COLS * NODE_DIM * sizeof(ushort);
    float*  Rb   = (float*)ws;                                    // 32 x 192 f32
    ws += (size_t)N_REL * H_DIM * sizeof(float);
    ushort* Pb   = (ushort*)ws;                                   // 100000 x 384 bf16

    build_b_kernel<<<(P_COLS * NODE_DIM + 255) / 256, 256, 0, stream>>>(W1, Bmat);
    rel_precompute_kernel<<<N_REL, H_DIM, 0, stream>>>(relation_emb, W1, b1, Rb);

    node_mfma_kernel<<<NBLK, 256, 0, stream>>>(all_embed, Bmat, Pb);

    edge_kernel<<<N_EDGES_C / 32, 256, 0, stream>>>(
        edge_index, edge_type, Pb, Rb, u, W2, b2, out);
}